// Round 10
// baseline (2689.320 us; speedup 1.0000x reference)
//
#include <hip/hip_runtime.h>
#include <hip/hip_bf16.h>

typedef __hip_bfloat16 bf16;
typedef short s8 __attribute__((ext_vector_type(8)));
typedef short sv4 __attribute__((ext_vector_type(4)));
typedef float f4 __attribute__((ext_vector_type(4)));
typedef int i4 __attribute__((ext_vector_type(4)));

#define BETA 0.125f
#define EPS 1e-5f

__device__ __forceinline__ void gld16(const void* g, void* l){
    __builtin_amdgcn_global_load_lds(
        (const __attribute__((address_space(1))) void*)g,
        (__attribute__((address_space(3))) void*)l, 16, 0, 0);
}

// ---------- fused prologue: all fp32->bf16 weight converts + x pad + cls row ----------
// segments (element index e over one flat grid; TOTAL = 9,658,368 = 37728*256):
//   [0,589824) wq | [589824,1179648) wk | [1179648,3538944) w_hop  -> B1
//   [3538944,4128768) w_enc -> we | [4128768,4718592) w_dec -> wd
//   [4718592,9633792) x -> g (rows >=6272 zero-padded)
//   [9633792,9658368) cls+pos -> t row 0 of each batch (fp32), guarded b<32
__global__ __launch_bounds__(256) void pre_k(
    const float* __restrict__ wq, const float* __restrict__ wk, const float* __restrict__ w_hop,
    const float* __restrict__ w_enc, const float* __restrict__ w_dec,
    const float* __restrict__ x, const float* __restrict__ cls, const float* __restrict__ pos,
    bf16* __restrict__ B1, bf16* __restrict__ we_, bf16* __restrict__ wd_,
    bf16* __restrict__ g_, float* __restrict__ t_)
{
    long e = (long)blockIdx.x*256 + threadIdx.x;
    if (e < 3538944L){
        float v;
        if (e < 589824L)        v = wq[e];
        else if (e < 1179648L)  v = wk[e - 589824L];
        else                    v = w_hop[e - 1179648L];
        B1[e] = __float2bfloat16(v);
    } else if (e < 4128768L){
        long i = e - 3538944L;  we_[i] = __float2bfloat16(w_enc[i]);
    } else if (e < 4718592L){
        long i = e - 4128768L;  wd_[i] = __float2bfloat16(w_dec[i]);
    } else if (e < 9633792L){
        long i = e - 4718592L;
        long row = i / 768;
        g_[i] = (row < 6272) ? __float2bfloat16(x[i]) : __float2bfloat16(0.f);
    } else {
        long i = e - 9633792L;
        int b = (int)(i / 768), c = (int)(i % 768);
        if (b < 32) t_[((long)b*197)*768 + c] = cls[c] + pos[c];
    }
}

// one-time zero of ALL of qT/kT (25.2 MB = 1,572,864 i4)
__global__ __launch_bounds__(256) void zqt_k(i4* __restrict__ p){
    p[(long)blockIdx.x*256 + threadIdx.x] = (i4){0,0,0,0};
}

// PER-STEP pad zero (r10 fix): qT/kT pad cells m in [192,256) of every
// [bh][z] row must be EXACT bf16 zeros before attn reads them. The r9 NaN:
// gemm1's fp32 partials (p2 alias) leave raw bytes there whose bf16
// interpretation can be NaN (exp=0xFF), and MFMA 0*NaN = NaN — "multiplied
// by P=0" does NOT neutralize them. Runs after ln_k (p2 consumed), before
// gemm0 (which rewrites valid m 192..196). 393,216 i4 -> 1536 blocks.
__global__ __launch_bounds__(256) void zpad_k(i4* __restrict__ qt){
    int t = blockIdx.x*256 + threadIdx.x;          // 0..393215
    int arr = t / 196608;                          // 0 = qT, 1 = kT
    int u = t - arr*196608;
    int bhz = u >> 3, slot = u & 7;                // 8 i4 = 64 shorts per row
    qt[(long)arr*786432 + (long)bhz*32 + 24 + slot] = (i4){0,0,0,0};
}

__global__ __launch_bounds__(256) void tr_k(const short* __restrict__ Bi, short* __restrict__ Bo){
    __shared__ short t[32][33];
    int i0 = blockIdx.x*32, j0 = blockIdx.y*32;
    int li = threadIdx.x & 31, lj = threadIdx.x >> 5;
    #pragma unroll
    for (int r=0;r<4;r++) t[lj+8*r][li] = Bi[(long)(i0+lj+8*r)*768 + j0+li];
    __syncthreads();
    #pragma unroll
    for (int r=0;r<4;r++) Bo[(long)(j0+lj+8*r)*4608 + i0+li] = t[li][lj+8*r];
}

// ---------- big MFMA GEMM (128x128 tile; used for encode/decode epilogues) ----------
// MODE 2: encode epilogue | MODE 3: decode epilogue
template<int MODE>
__global__ __launch_bounds__(256) void big_gemm(
    const short* __restrict__ A, int lda,
    const short* __restrict__ B, int ldb,
    float* __restrict__ Cf, bf16* __restrict__ Cb, int ldc,
    int K, int Nn, int Nm, int relu0, long zoff,
    const float* __restrict__ bias, const float* __restrict__ pos)
{
    const int f = blockIdx.x;
    const int npg = 16*Nn;
    const int grp = f / npg;
    const int first_m = grp*16;
    const int gs = (Nm - first_m < 16) ? (Nm - first_m) : 16;
    const int rem = f % npg;
    const int bm = first_m + rem % gs;
    const int bn = rem / gs;

    __shared__ short lsA[8192];   // 2 k-panels x (128 rows x 32 cols)
    __shared__ short lsB[8192];
    const int tid = threadIdx.x;
    const int w = tid>>6, l = tid&63;
    const int m0 = bm*128, n0 = bn*128;
    const int srow = tid>>2;                       // 0..63 (global row within half)
    const int qglob = ((tid&3) - (tid>>3)) & 3;    // swizzled source quadrant
    const int scol = qglob*8;                      // shorts
    int koff, Ks;
    if (MODE==1){ Ks = K>>1; koff = blockIdx.z * Ks; Cf += (size_t)blockIdx.z * zoff; }
    else        { Ks = K;    koff = 0; }
    const short* pa = A + (size_t)(m0+srow)*lda + koff + scol;
    const short* pb = B + (size_t)(n0+srow)*ldb + koff + scol;
    short* laP = lsA + w*512;
    short* lbP = lsB + w*512;
    const int wm = (w>>1)*64, wn = (w&1)*64;
    const int fr = l&15, fq = ((l>>4) + (fr>>1) & 3)*8;   // swizzled read quadrant
    f4 acc[4][4] = {};
    const int nk = Ks>>6;
    for (int kt=0; kt<nk; kt++){
        const size_t ko = (size_t)kt*64;
        const size_t ra = 64*(size_t)lda, rb = 64*(size_t)ldb;
        gld16(pa + ko,           laP);
        gld16(pa + ko + ra,      laP + 2048);
        gld16(pa + ko + 32,      laP + 4096);
        gld16(pa + ko + 32 + ra, laP + 6144);
        gld16(pb + ko,           lbP);
        gld16(pb + ko + rb,      lbP + 2048);
        gld16(pb + ko + 32,      lbP + 4096);
        gld16(pb + ko + 32 + rb, lbP + 6144);
        __syncthreads();
        #pragma unroll
        for (int ks=0; ks<2; ks++){
            s8 af[4], bfr[4];
            #pragma unroll
            for (int i=0;i<4;i++) af[i]  = *(const s8*)(lsA + ks*4096 + (wm+i*16+fr)*32 + fq);
            #pragma unroll
            for (int j=0;j<4;j++) bfr[j] = *(const s8*)(lsB + ks*4096 + (wn+j*16+fr)*32 + fq);
            #pragma unroll
            for (int i=0;i<4;i++)
                #pragma unroll
                for (int j=0;j<4;j++)
                    acc[i][j] = __builtin_amdgcn_mfma_f32_16x16x32_bf16(af[i], bfr[j], acc[i][j], 0,0,0);
        }
        __syncthreads();
    }
    const int er = (l>>4)*4;
    const int ec = l&15;
    #pragma unroll
    for (int i=0;i<4;i++){
        #pragma unroll
        for (int j=0;j<4;j++){
            int gr0 = m0 + wm + i*16 + er;
            int gc  = n0 + wn + j*16 + ec;
            #pragma unroll
            for (int r=0;r<4;r++){
                float v = acc[i][j][r];
                int gr = gr0 + r;
                if (MODE==0){
                    if (gc >= relu0) v = v>0.f ? v : 0.f;
                    Cb[(size_t)gr*ldc + gc] = __float2bfloat16(v);
                } else if (MODE==1){
                    Cf[(size_t)gr*ldc + gc] = v;
                } else if (MODE==2){
                    if (gr < 6272){
                        int b = gr/196, n = gr%196;
                        Cf[((size_t)b*197 + n + 1)*768 + gc] = v + bias[gc] + pos[(long)(n+1)*768+gc];
                    }
                } else {
                    if (gr < 6272) Cf[(size_t)gr*ldc + gc] = v + bias[gc];
                }
            }
        }
    }
}

// ---------- wide MFMA GEMM: C = A[M,K] @ B[N,K]^T  (round-2 verified, 59us) ----------
// BM=256, BN=128, BK=64, 256 threads = 4 waves (2M x 2N), WAVE TILE 128x64.
// Plain 2-barrier __syncthreads structure; 48KB LDS, 2 blocks/CU. Hand-
// pipelined variants (r1 ring@1blk, r3 dbuf@BK32, r4 counted-ring@BK32,
// r6 4-phase) ALL regressed vs this — GEMM scheduling is parked.
// MODE 0: C bf16, relu col>=relu0. PACK FUSION: for bn<12 (q/k columns) the
// epilogue ALSO writes the transposed value into qT/kT ([bh][64 z][256 m]
// bf16), replacing the separate pack_k kernel. qTs/kTs arrive via the
// (unused-in-MODE0) Cf/Cf2 args. Pad cells (m>=197) are zeroed per step by
// zpad_k (MUST be exact bf16 zeros — see zpad_k comment / r9 NaN).
// MODE 1: fp32 partials, K split 3 ways by blockIdx.z; z==2 writes Cf2.
template<int MODE>
__global__ __launch_bounds__(256, 2) void wide_gemm(
    const short* __restrict__ A, int lda,
    const short* __restrict__ B, int ldb,
    float* __restrict__ Cf, float* __restrict__ Cf2,
    bf16* __restrict__ Cb, int ldc,
    int K, int Nn, int Nm, int relu0, long zoff)
{
    const int f = blockIdx.x;
    const int npg = 16*Nn;
    const int grp = f / npg;
    const int first_m = grp*16;
    const int gs = (Nm - first_m < 16) ? (Nm - first_m) : 16;
    const int rem = f % npg;
    const int bm = first_m + rem % gs;
    const int bn = rem / gs;

    __shared__ short lsA[16384];  // 2 k-panels x 256 rows x 32 shorts
    __shared__ short lsB[8192];   // 2 k-panels x 128 rows x 32 shorts
    const int tid = threadIdx.x;
    const int w = tid>>6, l = tid&63;
    const int m0 = bm*256, n0 = bn*128;

    int Ks, koff; float* Cp = Cf;
    if (MODE==1){ Ks = K/3; koff = blockIdx.z * Ks;
                  Cp = (blockIdx.z==2) ? Cf2 : Cf + (size_t)blockIdx.z * zoff; }
    else        { Ks = K; koff = 0; }
    const int NT = Ks>>6;

    // Staging: LDS layout [panel p][row r][quadrant qd][8 shorts], linear dest
    // = lane*16B per sweep; bank swizzle: source quadrant qs=(qd-(r>>1))&3.
    const short* sA[4]; const short* sB[2];
    #pragma unroll
    for (int j=0;j<4;j++){
        int c = j*256 + tid;
        int r = (c>>2)&255, qd = c&3;
        int qs = (qd - (r>>1)) & 3;
        sA[j] = A + (size_t)(m0+r)*lda + koff + qs*8;
    }
    #pragma unroll
    for (int j=0;j<2;j++){
        int c = j*256 + tid;
        int r = (c>>2)&127, qd = c&3;
        int qs = (qd - (r>>1)) & 3;
        sB[j] = B + (size_t)(n0+r)*ldb + koff + qs*8;
    }

    const int wm = (w>>1)*128, wn = (w&1)*64;
    const int fr = l&15;
    const int fq = (((l>>4) + (fr>>1)) & 3)*8;   // swizzled read quadrant
    f4 acc[8][4] = {};

    for (int kt=0; kt<NT; kt++){
        const size_t ko = (size_t)kt*64;
        short* dA = lsA + w*512;
        short* dB = lsB + w*512;
        #pragma unroll
        for (int j=0;j<4;j++){
            gld16(sA[j]+ko,      dA + j*2048);
            gld16(sA[j]+ko+32,   dA + (j+4)*2048);
        }
        #pragma unroll
        for (int j=0;j<2;j++){
            gld16(sB[j]+ko,      dB + j*2048);
            gld16(sB[j]+ko+32,   dB + (j+2)*2048);
        }
        __syncthreads();
        #pragma unroll
        for (int ks=0; ks<2; ks++){
            s8 af[8], bfr[4];
            #pragma unroll
            for (int i=0;i<8;i++) af[i]  = *(const s8*)(lsA + ks*8192 + (wm+i*16+fr)*32 + fq);
            #pragma unroll
            for (int j=0;j<4;j++) bfr[j] = *(const s8*)(lsB + ks*4096 + (wn+j*16+fr)*32 + fq);
            #pragma unroll
            for (int i=0;i<8;i++)
                #pragma unroll
                for (int j=0;j<4;j++)
                    acc[i][j] = __builtin_amdgcn_mfma_f32_16x16x32_bf16(af[i], bfr[j], acc[i][j], 0,0,0);
        }
        __syncthreads();
    }

    const int er = (l>>4)*4;
    const int ec = l&15;
    const bool doTr = (MODE==0) && (bn < 12);
    short* qTs = (short*)Cf;
    short* kTs = (short*)Cf2;
    #pragma unroll
    for (int i=0;i<8;i++){
        int bArr[4], mgArr[4];
        if (doTr){
            #pragma unroll
            for (int r=0;r<4;r++){
                int gr = m0 + wm + i*16 + er + r;
                int bb = gr/197;            // magic-mul
                bArr[r] = bb; mgArr[r] = gr - bb*197;
            }
        }
        #pragma unroll
        for (int j=0;j<4;j++){
            int gr0 = m0 + wm + i*16 + er;
            int gc  = n0 + wn + j*16 + ec;
            #pragma unroll
            for (int r=0;r<4;r++){
                float v = acc[i][j][r];
                int gr = gr0 + r;
                if (MODE==0){
                    if (gc >= relu0) v = v>0.f ? v : 0.f;
                    bf16 bv = __float2bfloat16(v);
                    Cb[(size_t)gr*ldc + gc] = bv;
                    if (doTr && gr < 6304){
                        int qk = (gc < 768) ? gc : gc - 768;
                        short* base = (gc < 768) ? qTs : kTs;
                        int h = qk>>6, z = qk&63;
                        base[((size_t)(bArr[r]*12 + h))*16384 + (size_t)z*256 + mgArr[r]]
                            = *(short*)&bv;
                    }
                } else {
                    Cp[(size_t)gr*ldc + gc] = v;
                }
            }
        }
    }
}

// ---------- fused attention per (b,h) ----------
__global__ __launch_bounds__(256) void attn_k(
    short* __restrict__ qkh, const short* __restrict__ qT, const short* __restrict__ kT)
{
    __shared__ short Pl[64*232];
    __shared__ short Ptl[208*72];
    const int bh = blockIdx.x, b = bh/12, h = bh%12;
    const int tid = threadIdx.x, w = tid>>6, l = tid&63;
    const int lr = l&15, lq = l>>4;
    const size_t qcol = (size_t)h*64, kcol = 768 + qcol;
    const size_t rbase = (size_t)b*197*4608;
    const short* qTp = qT + (size_t)bh*16384;
    const short* kTp = kT + (size_t)bh*16384;

    for (int i=tid; i<64*16; i+=256){ int r=i>>4, c=208+(i&15); Pl[r*232+c]=0; }

    f4 ak[13];
    #pragma unroll
    for (int t=0;t<13;t++) ak[t] = (f4){0.f,0.f,0.f,0.f};

    for (int iter=0; iter<4; iter++){
        const int m0 = iter*64;
        f4 S[13];
        #pragma unroll
        for (int t=0;t<13;t++) S[t] = (f4){0.f,0.f,0.f,0.f};
        const int mrow = m0 + w*16 + lr;
        #pragma unroll
        for (int ks=0; ks<2; ks++){
            s8 af = *(const s8*)(qkh + rbase + (size_t)mrow*4608 + qcol + ks*32 + lq*8);
            #pragma unroll
            for (int t=0;t<13;t++){
                s8 bf = *(const s8*)(qkh + rbase + (size_t)(t*16+lr)*4608 + kcol + ks*32 + lq*8);
                S[t] = __builtin_amdgcn_mfma_f32_16x16x32_bf16(af, bf, S[t], 0,0,0);
            }
        }
        __syncthreads();
        const int mbase = w*16 + lq*4;
        #pragma unroll
        for (int r=0;r<4;r++){
            float mx = -1e30f;
            #pragma unroll
            for (int t=0;t<13;t++){
                float v = S[t][r]*BETA;
                if (t==12 && lr>=5) v = -1e30f;
                S[t][r] = v;
                mx = fmaxf(mx, v);
            }
            mx = fmaxf(mx, __shfl_xor(mx,1,64)); mx = fmaxf(mx, __shfl_xor(mx,2,64));
            mx = fmaxf(mx, __shfl_xor(mx,4,64)); mx = fmaxf(mx, __shfl_xor(mx,8,64));
            float sm = 0.f;
            #pragma unroll
            for (int t=0;t<13;t++){ float e = __expf(S[t][r]-mx); S[t][r]=e; sm+=e; }
            sm += __shfl_xor(sm,1,64); sm += __shfl_xor(sm,2,64);
            sm += __shfl_xor(sm,4,64); sm += __shfl_xor(sm,8,64);
            float inv = 1.f/sm;
            bool valid = (m0 + mbase + r) < 197;
            #pragma unroll
            for (int t=0;t<13;t++) S[t][r] = valid ? S[t][r]*inv : 0.f;
        }
        #pragma unroll
        for (int t=0;t<13;t++){
            int c = t*16 + lr;
            short pb[4];
            #pragma unroll
            for (int r=0;r<4;r++){
                bf16 bv = __float2bfloat16(S[t][r]);
                pb[r] = *(short*)&bv;
                Pl[(mbase+r)*232 + c] = pb[r];
            }
            *(sv4*)(Ptl + c*72 + mbase) = (sv4){pb[0],pb[1],pb[2],pb[3]};
        }
        __syncthreads();
        f4 aq[4];
        #pragma unroll
        for (int t=0;t<4;t++) aq[t] = (f4){0.f,0.f,0.f,0.f};
        #pragma unroll
        for (int ks=0; ks<7; ks++){
            s8 af = *(const s8*)(kTp + (w*16+lr)*256 + ks*32 + lq*8);
            #pragma unroll
            for (int mt=0;mt<4;mt++){
                s8 bf = *(const s8*)(Pl + (mt*16+lr)*232 + ks*32 + lq*8);
                aq[mt] = __builtin_amdgcn_mfma_f32_16x16x32_bf16(af, bf, aq[mt], 0,0,0);
            }
        }
        #pragma unroll
        for (int mt=0;mt<4;mt++){
            int mg = m0 + mt*16 + lr;
            if (mg < 197){
                sv4 pv;
                #pragma unroll
                for (int r=0;r<4;r++){ bf16 bv=__float2bfloat16(aq[mt][r]); pv[r]=*(short*)&bv; }
                *(sv4*)(qkh + rbase + (size_t)mg*4608 + qcol + w*16 + lq*4) = pv;
            }
        }
        #pragma unroll
        for (int ks=0; ks<2; ks++){
            s8 bf = *(const s8*)(qTp + (w*16+lr)*256 + m0 + ks*32 + lq*8);
            #pragma unroll
            for (int t=0;t<13;t++){
                s8 af = *(const s8*)(Ptl + (t*16+lr)*72 + ks*32 + lq*8);
                ak[t] = __builtin_amdgcn_mfma_f32_16x16x32_bf16(af, bf, ak[t], 0,0,0);
            }
        }
    }
    #pragma unroll
    for (int t=0;t<13;t++){
        #pragma unroll
        for (int r=0;r<4;r++){
            int n = t*16 + lq*4 + r;
            if (n < 197)
                *(bf16*)(qkh + rbase + (size_t)n*4608 + kcol + w*16 + lr) = __float2bfloat16(ak[t][r]);
        }
    }
}

// ---------- LN (optionally folds 3 split-K partials into t first) ----------
__global__ __launch_bounds__(256) void ln_k(
    float* __restrict__ in, bf16* __restrict__ out,
    const float* __restrict__ p0, const float* __restrict__ p1, const float* __restrict__ p2,
    const float* __restrict__ scale, const float* __restrict__ bias,
    int scalar_scale, int rowmap, int addp, int writet)
{
    int r = blockIdx.x;
    long src = rowmap ? ((long)(r/196)*197 + r%196 + 1) : (long)r;
    float* xr = in + src*768;
    int tid = threadIdx.x;
    float v0 = xr[tid], v1 = xr[tid+256], v2 = xr[tid+512];
    if (addp){
        const float* a = p0 + src*768;
        const float* b = p1 + src*768;
        const float* c = p2 + src*768;
        v0 += a[tid]     + b[tid]     + c[tid];
        v1 += a[tid+256] + b[tid+256] + c[tid+256];
        v2 += a[tid+512] + b[tid+512] + c[tid+512];
        if (writet){ xr[tid]=v0; xr[tid+256]=v1; xr[tid+512]=v2; }
    }
    __shared__ float red[4];
    float s = v0+v1+v2;
    #pragma unroll
    for (int o=1;o<64;o<<=1) s += __shfl_xor(s, o, 64);
    if ((tid&63)==0) red[tid>>6] = s;
    __syncthreads();
    float mu = (red[0]+red[1]+red[2]+red[3]) * (1.f/768.f);
    float d0=v0-mu, d1=v1-mu, d2=v2-mu;
    float q = d0*d0 + d1*d1 + d2*d2;
    #pragma unroll
    for (int o=1;o<64;o<<=1) q += __shfl_xor(q, o, 64);
    __syncthreads();
    if ((tid&63)==0) red[tid>>6] = q;
    __syncthreads();
    float ms = (red[0]+red[1]+red[2]+red[3]) * (1.f/768.f);
    float inv = rsqrtf(ms + EPS);
    bf16* o_ = out + (long)r*768;
    float s0 = scalar_scale ? scale[0] : scale[tid];
    float s1 = scalar_scale ? s0 : scale[tid+256];
    float s2 = scalar_scale ? s0 : scale[tid+512];
    o_[tid]     = __float2bfloat16(d0*inv*s0 + bias[tid]);
    o_[tid+256] = __float2bfloat16(d1*inv*s1 + bias[tid+256]);
    o_[tid+512] = __float2bfloat16(d2*inv*s2 + bias[tid+512]);
}

extern "C" void kernel_launch(void* const* d_in, const int* in_sizes, int n_in,
                              void* d_out, int out_size, void* d_ws, size_t ws_size,
                              hipStream_t stream) {
    const float* x       = (const float*)d_in[0];
    const float* w_enc   = (const float*)d_in[1];
    const float* b_enc   = (const float*)d_in[2];
    const float* cls_tok = (const float*)d_in[3];
    const float* pos     = (const float*)d_in[4];
    const float* eln_g   = (const float*)d_in[5];
    const float* eln_b   = (const float*)d_in[6];
    const float* wq      = (const float*)d_in[7];
    const float* wk      = (const float*)d_in[8];
    const float* w_hop   = (const float*)d_in[9];
    const float* dln_w   = (const float*)d_in[10];
    const float* dln_b   = (const float*)d_in[11];
    const float* w_dec   = (const float*)d_in[12];
    const float* b_dec   = (const float*)d_in[13];
    float* out = (float*)d_out;

    float* t_  = (float*)d_ws;                    // [6400,768] fp32
    bf16* g_   = (bf16*)(t_ + 6400L*768);         // [6400,768]
    bf16* qkh  = g_ + 6400L*768;                  // [6400,4608] = q|k|h (aq|ak overwrite q|k)
    bf16* qT   = qkh + 6400L*4608;                // [384,64,256]
    bf16* kT   = qT + 384L*16384;                 // [384,64,256]
    float* p0  = (float*)(kT + 384L*16384);       // [6400,768] split-K partial z=0
    float* p1  = p0 + 6400L*768;                  // [6400,768] split-K partial z=1
    bf16* B1   = (bf16*)(p1 + 6400L*768);         // [4608,768]  wq|wk|whop
    bf16* B2   = B1 + 4608L*768;                  // [768,4608]  = B1^T
    bf16* we_  = B2 + 768L*4608;                  // [768,768]
    bf16* wd_  = we_ + 768L*768;                  // [768,768]
    // z=2 partial aliases qT/kT scratch: dead between attn_k (last reader)
    // and the next step's wide_gemm<0> epilogue re-write; wide_gemm<1> fills
    // it fully before ln_k reads it. Its bytes in qT/kT pad cells can be
    // bf16-NaN patterns -> zpad_k re-zeroes pads每 step (r9 lesson).
    float* p2  = (float*)qT;

    dim3 blk(256);
    const long ZOFF = 6400L*768;

    // fused prologue + one-time qT/kT zero
    pre_k<<<dim3(37728), blk, 0, stream>>>(wq, wk, w_hop, w_enc, w_dec, x, cls_tok, pos,
                                           B1, we_, wd_, g_, t_);
    zqt_k<<<dim3(6144), blk, 0, stream>>>((i4*)qT);
    tr_k<<<dim3(144,24), blk, 0, stream>>>((const short*)B1, (short*)B2);

    big_gemm<2><<<dim3(300), blk, 0, stream>>>((const short*)g_, 768, (const short*)we_, 768,
                                               t_, nullptr, 768, 768, 6, 50, 0, 0, b_enc, pos);

    for (int step=0; step<12; step++){
        ln_k<<<dim3(6304), blk, 0, stream>>>(t_, g_, p0, p1, p2, eln_g, eln_b, 1, 0, step>0, 1);
        // re-zero qT/kT pad cells (p2 consumed by ln_k above; gemm0 below
        // rewrites the valid cells). MUST precede attn_k.
        zpad_k<<<dim3(1536), blk, 0, stream>>>((i4*)qT);
        // [6400,4608] = g @ [wq|wk|whop]^T; epilogue also scatters q/k into qT/kT
        wide_gemm<0><<<dim3(900), blk, 0, stream>>>((const short*)g_, 768, (const short*)B1, 768,
                                                    (float*)qT, (float*)kT, qkh, 4608, 768, 36, 25, 1536, 0);
        attn_k<<<dim3(384), blk, 0, stream>>>((short*)qkh, (const short*)qT, (const short*)kT);
        // [6400,768] = [aq|ak|relu h] @ B2^T-form, K=4608 split 3: 150 x 3 blocks
        wide_gemm<1><<<dim3(150,1,3), blk, 0, stream>>>((const short*)qkh, 4608, (const short*)B2, 4608,
                                                        p0, p2, nullptr, 768, 4608, 6, 25, 0, ZOFF);
    }

    ln_k<<<dim3(6272), blk, 0, stream>>>(t_, g_, p0, p1, p2, dln_w, dln_b, 0, 1, 1, 0);
    big_gemm<3><<<dim3(300), blk, 0, stream>>>((const short*)g_, 768, (const short*)wd_, 768,
                                               out, nullptr, 768, 768, 6, 50, 0, 0, b_dec, nullptr);
}

// Round 11
// 2383.222 us; speedup vs baseline: 1.1284x; 1.1284x over previous
//
#include <hip/hip_runtime.h>
#include <hip/hip_bf16.h>

typedef __hip_bfloat16 bf16;
typedef short s8 __attribute__((ext_vector_type(8)));
typedef short sv4 __attribute__((ext_vector_type(4)));
typedef float f4 __attribute__((ext_vector_type(4)));

#define BETA 0.125f
#define EPS 1e-5f

__device__ __forceinline__ void gld16(const void* g, void* l){
    __builtin_amdgcn_global_load_lds(
        (const __attribute__((address_space(1))) void*)g,
        (__attribute__((address_space(3))) void*)l, 16, 0, 0);
}

// ---------- fused prologue: all fp32->bf16 weight converts + x pad + cls row ----------
// segments (element index e over one flat grid; TOTAL = 9,658,368 = 37728*256):
//   [0,589824) wq | [589824,1179648) wk | [1179648,3538944) w_hop  -> B1
//   [3538944,4128768) w_enc -> we | [4128768,4718592) w_dec -> wd
//   [4718592,9633792) x -> g (rows >=6272 zero-padded)
//   [9633792,9658368) cls+pos -> t row 0 of each batch (fp32), guarded b<32
__global__ __launch_bounds__(256) void pre_k(
    const float* __restrict__ wq, const float* __restrict__ wk, const float* __restrict__ w_hop,
    const float* __restrict__ w_enc, const float* __restrict__ w_dec,
    const float* __restrict__ x, const float* __restrict__ cls, const float* __restrict__ pos,
    bf16* __restrict__ B1, bf16* __restrict__ we_, bf16* __restrict__ wd_,
    bf16* __restrict__ g_, float* __restrict__ t_)
{
    long e = (long)blockIdx.x*256 + threadIdx.x;
    if (e < 3538944L){
        float v;
        if (e < 589824L)        v = wq[e];
        else if (e < 1179648L)  v = wk[e - 589824L];
        else                    v = w_hop[e - 1179648L];
        B1[e] = __float2bfloat16(v);
    } else if (e < 4128768L){
        long i = e - 3538944L;  we_[i] = __float2bfloat16(w_enc[i]);
    } else if (e < 4718592L){
        long i = e - 4128768L;  wd_[i] = __float2bfloat16(w_dec[i]);
    } else if (e < 9633792L){
        long i = e - 4718592L;
        long row = i / 768;
        g_[i] = (row < 6272) ? __float2bfloat16(x[i]) : __float2bfloat16(0.f);
    } else {
        long i = e - 9633792L;
        int b = (int)(i / 768), c = (int)(i % 768);
        if (b < 32) t_[((long)b*197)*768 + c] = cls[c] + pos[c];
    }
}

__global__ __launch_bounds__(256) void tr_k(const short* __restrict__ Bi, short* __restrict__ Bo){
    __shared__ short t[32][33];
    int i0 = blockIdx.x*32, j0 = blockIdx.y*32;
    int li = threadIdx.x & 31, lj = threadIdx.x >> 5;
    #pragma unroll
    for (int r=0;r<4;r++) t[lj+8*r][li] = Bi[(long)(i0+lj+8*r)*768 + j0+li];
    __syncthreads();
    #pragma unroll
    for (int r=0;r<4;r++) Bo[(long)(j0+lj+8*r)*4608 + i0+li] = t[li][lj+8*r];
}

// ---------- big MFMA GEMM (128x128 tile; used for encode/decode epilogues) ----------
// MODE 2: encode epilogue | MODE 3: decode epilogue
template<int MODE>
__global__ __launch_bounds__(256) void big_gemm(
    const short* __restrict__ A, int lda,
    const short* __restrict__ B, int ldb,
    float* __restrict__ Cf, bf16* __restrict__ Cb, int ldc,
    int K, int Nn, int Nm, int relu0, long zoff,
    const float* __restrict__ bias, const float* __restrict__ pos)
{
    const int f = blockIdx.x;
    const int npg = 16*Nn;
    const int grp = f / npg;
    const int first_m = grp*16;
    const int gs = (Nm - first_m < 16) ? (Nm - first_m) : 16;
    const int rem = f % npg;
    const int bm = first_m + rem % gs;
    const int bn = rem / gs;

    __shared__ short lsA[8192];   // 2 k-panels x (128 rows x 32 cols)
    __shared__ short lsB[8192];
    const int tid = threadIdx.x;
    const int w = tid>>6, l = tid&63;
    const int m0 = bm*128, n0 = bn*128;
    const int srow = tid>>2;                       // 0..63 (global row within half)
    const int qglob = ((tid&3) - (tid>>3)) & 3;    // swizzled source quadrant
    const int scol = qglob*8;                      // shorts
    int koff, Ks;
    if (MODE==1){ Ks = K>>1; koff = blockIdx.z * Ks; Cf += (size_t)blockIdx.z * zoff; }
    else        { Ks = K;    koff = 0; }
    const short* pa = A + (size_t)(m0+srow)*lda + koff + scol;
    const short* pb = B + (size_t)(n0+srow)*ldb + koff + scol;
    short* laP = lsA + w*512;
    short* lbP = lsB + w*512;
    const int wm = (w>>1)*64, wn = (w&1)*64;
    const int fr = l&15, fq = ((l>>4) + (fr>>1) & 3)*8;   // swizzled read quadrant
    f4 acc[4][4] = {};
    const int nk = Ks>>6;
    for (int kt=0; kt<nk; kt++){
        const size_t ko = (size_t)kt*64;
        const size_t ra = 64*(size_t)lda, rb = 64*(size_t)ldb;
        gld16(pa + ko,           laP);
        gld16(pa + ko + ra,      laP + 2048);
        gld16(pa + ko + 32,      laP + 4096);
        gld16(pa + ko + 32 + ra, laP + 6144);
        gld16(pb + ko,           lbP);
        gld16(pb + ko + rb,      lbP + 2048);
        gld16(pb + ko + 32,      lbP + 4096);
        gld16(pb + ko + 32 + rb, lbP + 6144);
        __syncthreads();
        #pragma unroll
        for (int ks=0; ks<2; ks++){
            s8 af[4], bfr[4];
            #pragma unroll
            for (int i=0;i<4;i++) af[i]  = *(const s8*)(lsA + ks*4096 + (wm+i*16+fr)*32 + fq);
            #pragma unroll
            for (int j=0;j<4;j++) bfr[j] = *(const s8*)(lsB + ks*4096 + (wn+j*16+fr)*32 + fq);
            #pragma unroll
            for (int i=0;i<4;i++)
                #pragma unroll
                for (int j=0;j<4;j++)
                    acc[i][j] = __builtin_amdgcn_mfma_f32_16x16x32_bf16(af[i], bfr[j], acc[i][j], 0,0,0);
        }
        __syncthreads();
    }
    const int er = (l>>4)*4;
    const int ec = l&15;
    #pragma unroll
    for (int i=0;i<4;i++){
        #pragma unroll
        for (int j=0;j<4;j++){
            int gr0 = m0 + wm + i*16 + er;
            int gc  = n0 + wn + j*16 + ec;
            #pragma unroll
            for (int r=0;r<4;r++){
                float v = acc[i][j][r];
                int gr = gr0 + r;
                if (MODE==0){
                    if (gc >= relu0) v = v>0.f ? v : 0.f;
                    Cb[(size_t)gr*ldc + gc] = __float2bfloat16(v);
                } else if (MODE==1){
                    Cf[(size_t)gr*ldc + gc] = v;
                } else if (MODE==2){
                    if (gr < 6272){
                        int b = gr/196, n = gr%196;
                        Cf[((size_t)b*197 + n + 1)*768 + gc] = v + bias[gc] + pos[(long)(n+1)*768+gc];
                    }
                } else {
                    if (gr < 6272) Cf[(size_t)gr*ldc + gc] = v + bias[gc];
                }
            }
        }
    }
}

// ---------- wide MFMA GEMM: C = A[M,K] @ B[N,K]^T  (round-2/8 verified, 59us) ----------
// BM=256, BN=128, BK=64, 256 threads = 4 waves (2M x 2N), WAVE TILE 128x64.
// Plain 2-barrier __syncthreads structure; 48KB LDS, 2 blocks/CU.
// CONDEMNED alternatives (measured): hand pipelines (r1/r3/r4/r6 — all
// regressed or livelocked); epilogue transpose-scatter (r10: 2B stores at
// 512B stride -> +29MB write amplification, gemm0 59->95us).
// MODE 0: C bf16, relu col>=relu0 | MODE 1: fp32 partials, K split 3 ways by
// blockIdx.z; z==2 writes Cf2 (third partial in scratch aliasing qT/kT).
template<int MODE>
__global__ __launch_bounds__(256, 2) void wide_gemm(
    const short* __restrict__ A, int lda,
    const short* __restrict__ B, int ldb,
    float* __restrict__ Cf, float* __restrict__ Cf2,
    bf16* __restrict__ Cb, int ldc,
    int K, int Nn, int Nm, int relu0, long zoff)
{
    const int f = blockIdx.x;
    const int npg = 16*Nn;
    const int grp = f / npg;
    const int first_m = grp*16;
    const int gs = (Nm - first_m < 16) ? (Nm - first_m) : 16;
    const int rem = f % npg;
    const int bm = first_m + rem % gs;
    const int bn = rem / gs;

    __shared__ short lsA[16384];  // 2 k-panels x 256 rows x 32 shorts
    __shared__ short lsB[8192];   // 2 k-panels x 128 rows x 32 shorts
    const int tid = threadIdx.x;
    const int w = tid>>6, l = tid&63;
    const int m0 = bm*256, n0 = bn*128;

    int Ks, koff; float* Cp = Cf;
    if (MODE==1){ Ks = K/3; koff = blockIdx.z * Ks;
                  Cp = (blockIdx.z==2) ? Cf2 : Cf + (size_t)blockIdx.z * zoff; }
    else        { Ks = K; koff = 0; }
    const int NT = Ks>>6;

    // Staging: LDS layout [panel p][row r][quadrant qd][8 shorts], linear dest
    // = lane*16B per sweep; bank swizzle: source quadrant qs=(qd-(r>>1))&3.
    const short* sA[4]; const short* sB[2];
    #pragma unroll
    for (int j=0;j<4;j++){
        int c = j*256 + tid;
        int r = (c>>2)&255, qd = c&3;
        int qs = (qd - (r>>1)) & 3;
        sA[j] = A + (size_t)(m0+r)*lda + koff + qs*8;
    }
    #pragma unroll
    for (int j=0;j<2;j++){
        int c = j*256 + tid;
        int r = (c>>2)&127, qd = c&3;
        int qs = (qd - (r>>1)) & 3;
        sB[j] = B + (size_t)(n0+r)*ldb + koff + qs*8;
    }

    const int wm = (w>>1)*128, wn = (w&1)*64;
    const int fr = l&15;
    const int fq = (((l>>4) + (fr>>1)) & 3)*8;   // swizzled read quadrant
    f4 acc[8][4] = {};

    for (int kt=0; kt<NT; kt++){
        const size_t ko = (size_t)kt*64;
        short* dA = lsA + w*512;
        short* dB = lsB + w*512;
        #pragma unroll
        for (int j=0;j<4;j++){
            gld16(sA[j]+ko,      dA + j*2048);
            gld16(sA[j]+ko+32,   dA + (j+4)*2048);
        }
        #pragma unroll
        for (int j=0;j<2;j++){
            gld16(sB[j]+ko,      dB + j*2048);
            gld16(sB[j]+ko+32,   dB + (j+2)*2048);
        }
        __syncthreads();
        #pragma unroll
        for (int ks=0; ks<2; ks++){
            s8 af[8], bfr[4];
            #pragma unroll
            for (int i=0;i<8;i++) af[i]  = *(const s8*)(lsA + ks*8192 + (wm+i*16+fr)*32 + fq);
            #pragma unroll
            for (int j=0;j<4;j++) bfr[j] = *(const s8*)(lsB + ks*4096 + (wn+j*16+fr)*32 + fq);
            #pragma unroll
            for (int i=0;i<8;i++)
                #pragma unroll
                for (int j=0;j<4;j++)
                    acc[i][j] = __builtin_amdgcn_mfma_f32_16x16x32_bf16(af[i], bfr[j], acc[i][j], 0,0,0);
        }
        __syncthreads();
    }

    const int er = (l>>4)*4;
    const int ec = l&15;
    #pragma unroll
    for (int i=0;i<8;i++){
        #pragma unroll
        for (int j=0;j<4;j++){
            int gr0 = m0 + wm + i*16 + er;
            int gc  = n0 + wn + j*16 + ec;
            #pragma unroll
            for (int r=0;r<4;r++){
                float v = acc[i][j][r];
                int gr = gr0 + r;
                if (MODE==0){
                    if (gc >= relu0) v = v>0.f ? v : 0.f;
                    Cb[(size_t)gr*ldc + gc] = __float2bfloat16(v);
                } else {
                    Cp[(size_t)gr*ldc + gc] = v;
                }
            }
        }
    }
}

// ---------- pack q^T / k^T : [384][64 z][256 m] bf16, zero-padded ----------
__global__ __launch_bounds__(256) void pack_k(const short* __restrict__ qkh,
                                              short* __restrict__ qT, short* __restrict__ kT){
    __shared__ short tq[64][65];
    __shared__ short tk[64][65];
    const int bh = blockIdx.x, b = bh/12, h = bh%12;
    const int mc = blockIdx.y*64;
    const int tid = threadIdx.x;
    #pragma unroll
    for (int e=0;e<16;e++){
        int i = tid + e*256; int r = i>>6, c = i&63;
        int mg = mc + r;
        short vq = 0, vk = 0;
        if (mg < 197){
            size_t base = (size_t)(b*197+mg)*4608 + h*64 + c;
            vq = qkh[base]; vk = qkh[base+768];
        }
        tq[r][c] = vq; tk[r][c] = vk;
    }
    __syncthreads();
    #pragma unroll
    for (int e=0;e<16;e++){
        int i = tid + e*256; int zr = i>>6, cm = i&63;
        size_t o = (size_t)bh*16384 + (size_t)zr*256 + mc + cm;
        qT[o] = tq[cm][zr];
        kT[o] = tk[cm][zr];
    }
}

// ---------- fused attention per (b,h) ----------
__global__ __launch_bounds__(256) void attn_k(
    short* __restrict__ qkh, const short* __restrict__ qT, const short* __restrict__ kT)
{
    __shared__ short Pl[64*232];
    __shared__ short Ptl[208*72];
    const int bh = blockIdx.x, b = bh/12, h = bh%12;
    const int tid = threadIdx.x, w = tid>>6, l = tid&63;
    const int lr = l&15, lq = l>>4;
    const size_t qcol = (size_t)h*64, kcol = 768 + qcol;
    const size_t rbase = (size_t)b*197*4608;
    const short* qTp = qT + (size_t)bh*16384;
    const short* kTp = kT + (size_t)bh*16384;

    for (int i=tid; i<64*16; i+=256){ int r=i>>4, c=208+(i&15); Pl[r*232+c]=0; }

    f4 ak[13];
    #pragma unroll
    for (int t=0;t<13;t++) ak[t] = (f4){0.f,0.f,0.f,0.f};

    for (int iter=0; iter<4; iter++){
        const int m0 = iter*64;
        f4 S[13];
        #pragma unroll
        for (int t=0;t<13;t++) S[t] = (f4){0.f,0.f,0.f,0.f};
        const int mrow = m0 + w*16 + lr;
        #pragma unroll
        for (int ks=0; ks<2; ks++){
            s8 af = *(const s8*)(qkh + rbase + (size_t)mrow*4608 + qcol + ks*32 + lq*8);
            #pragma unroll
            for (int t=0;t<13;t++){
                s8 bf = *(const s8*)(qkh + rbase + (size_t)(t*16+lr)*4608 + kcol + ks*32 + lq*8);
                S[t] = __builtin_amdgcn_mfma_f32_16x16x32_bf16(af, bf, S[t], 0,0,0);
            }
        }
        __syncthreads();
        const int mbase = w*16 + lq*4;
        #pragma unroll
        for (int r=0;r<4;r++){
            float mx = -1e30f;
            #pragma unroll
            for (int t=0;t<13;t++){
                float v = S[t][r]*BETA;
                if (t==12 && lr>=5) v = -1e30f;
                S[t][r] = v;
                mx = fmaxf(mx, v);
            }
            mx = fmaxf(mx, __shfl_xor(mx,1,64)); mx = fmaxf(mx, __shfl_xor(mx,2,64));
            mx = fmaxf(mx, __shfl_xor(mx,4,64)); mx = fmaxf(mx, __shfl_xor(mx,8,64));
            float sm = 0.f;
            #pragma unroll
            for (int t=0;t<13;t++){ float e = __expf(S[t][r]-mx); S[t][r]=e; sm+=e; }
            sm += __shfl_xor(sm,1,64); sm += __shfl_xor(sm,2,64);
            sm += __shfl_xor(sm,4,64); sm += __shfl_xor(sm,8,64);
            float inv = 1.f/sm;
            bool valid = (m0 + mbase + r) < 197;
            #pragma unroll
            for (int t=0;t<13;t++) S[t][r] = valid ? S[t][r]*inv : 0.f;
        }
        #pragma unroll
        for (int t=0;t<13;t++){
            int c = t*16 + lr;
            short pb[4];
            #pragma unroll
            for (int r=0;r<4;r++){
                bf16 bv = __float2bfloat16(S[t][r]);
                pb[r] = *(short*)&bv;
                Pl[(mbase+r)*232 + c] = pb[r];
            }
            *(sv4*)(Ptl + c*72 + mbase) = (sv4){pb[0],pb[1],pb[2],pb[3]};
        }
        __syncthreads();
        f4 aq[4];
        #pragma unroll
        for (int t=0;t<4;t++) aq[t] = (f4){0.f,0.f,0.f,0.f};
        #pragma unroll
        for (int ks=0; ks<7; ks++){
            s8 af = *(const s8*)(kTp + (w*16+lr)*256 + ks*32 + lq*8);
            #pragma unroll
            for (int mt=0;mt<4;mt++){
                s8 bf = *(const s8*)(Pl + (mt*16+lr)*232 + ks*32 + lq*8);
                aq[mt] = __builtin_amdgcn_mfma_f32_16x16x32_bf16(af, bf, aq[mt], 0,0,0);
            }
        }
        #pragma unroll
        for (int mt=0;mt<4;mt++){
            int mg = m0 + mt*16 + lr;
            if (mg < 197){
                sv4 pv;
                #pragma unroll
                for (int r=0;r<4;r++){ bf16 bv=__float2bfloat16(aq[mt][r]); pv[r]=*(short*)&bv; }
                *(sv4*)(qkh + rbase + (size_t)mg*4608 + qcol + w*16 + lq*4) = pv;
            }
        }
        #pragma unroll
        for (int ks=0; ks<2; ks++){
            s8 bf = *(const s8*)(qTp + (w*16+lr)*256 + m0 + ks*32 + lq*8);
            #pragma unroll
            for (int t=0;t<13;t++){
                s8 af = *(const s8*)(Ptl + (t*16+lr)*72 + ks*32 + lq*8);
                ak[t] = __builtin_amdgcn_mfma_f32_16x16x32_bf16(af, bf, ak[t], 0,0,0);
            }
        }
    }
    #pragma unroll
    for (int t=0;t<13;t++){
        #pragma unroll
        for (int r=0;r<4;r++){
            int n = t*16 + lq*4 + r;
            if (n < 197)
                *(bf16*)(qkh + rbase + (size_t)n*4608 + kcol + w*16 + lr) = __float2bfloat16(ak[t][r]);
        }
    }
}

// ---------- LN, float4-vectorized (G13): 192 threads, 16B/lane streams ----------
// Folds 3 split-K partials into t first when addp. Same math as the scalar
// version (r8-verified), only the lane mapping changed: thread i owns float4
// column slot i (768 = 192*4). Reduction: 64-lane shfl + 3-wave LDS combine.
__global__ __launch_bounds__(192) void ln_k(
    float* __restrict__ in, bf16* __restrict__ out,
    const float* __restrict__ p0, const float* __restrict__ p1, const float* __restrict__ p2,
    const float* __restrict__ scale, const float* __restrict__ bias,
    int scalar_scale, int rowmap, int addp, int writet)
{
    int r = blockIdx.x;
    long src = rowmap ? ((long)(r/196)*197 + r%196 + 1) : (long)r;
    float4* xr = (float4*)(in + src*768);
    int tid = threadIdx.x;
    float4 v = xr[tid];
    if (addp){
        float4 a = ((const float4*)(p0 + src*768))[tid];
        float4 b = ((const float4*)(p1 + src*768))[tid];
        float4 c = ((const float4*)(p2 + src*768))[tid];
        v.x += a.x + b.x + c.x;
        v.y += a.y + b.y + c.y;
        v.z += a.z + b.z + c.z;
        v.w += a.w + b.w + c.w;
        if (writet) xr[tid] = v;
    }
    __shared__ float red[3];
    float s = v.x + v.y + v.z + v.w;
    #pragma unroll
    for (int o=1;o<64;o<<=1) s += __shfl_xor(s, o, 64);
    if ((tid&63)==0) red[tid>>6] = s;
    __syncthreads();
    float mu = (red[0]+red[1]+red[2]) * (1.f/768.f);
    float dx = v.x-mu, dy = v.y-mu, dz = v.z-mu, dw = v.w-mu;
    float q = dx*dx + dy*dy + dz*dz + dw*dw;
    #pragma unroll
    for (int o=1;o<64;o<<=1) q += __shfl_xor(q, o, 64);
    __syncthreads();
    if ((tid&63)==0) red[tid>>6] = q;
    __syncthreads();
    float ms = (red[0]+red[1]+red[2]) * (1.f/768.f);
    float inv = rsqrtf(ms + EPS);
    float4 s4, b4;
    if (scalar_scale){ float s0 = scale[0]; s4 = make_float4(s0,s0,s0,s0); }
    else              s4 = ((const float4*)scale)[tid];
    b4 = ((const float4*)bias)[tid];
    bf16 o0 = __float2bfloat16(dx*inv*s4.x + b4.x);
    bf16 o1 = __float2bfloat16(dy*inv*s4.y + b4.y);
    bf16 o2 = __float2bfloat16(dz*inv*s4.z + b4.z);
    bf16 o3 = __float2bfloat16(dw*inv*s4.w + b4.w);
    *(sv4*)(out + (long)r*768 + tid*4) =
        (sv4){*(short*)&o0, *(short*)&o1, *(short*)&o2, *(short*)&o3};
}

extern "C" void kernel_launch(void* const* d_in, const int* in_sizes, int n_in,
                              void* d_out, int out_size, void* d_ws, size_t ws_size,
                              hipStream_t stream) {
    const float* x       = (const float*)d_in[0];
    const float* w_enc   = (const float*)d_in[1];
    const float* b_enc   = (const float*)d_in[2];
    const float* cls_tok = (const float*)d_in[3];
    const float* pos     = (const float*)d_in[4];
    const float* eln_g   = (const float*)d_in[5];
    const float* eln_b   = (const float*)d_in[6];
    const float* wq      = (const float*)d_in[7];
    const float* wk      = (const float*)d_in[8];
    const float* w_hop   = (const float*)d_in[9];
    const float* dln_w   = (const float*)d_in[10];
    const float* dln_b   = (const float*)d_in[11];
    const float* w_dec   = (const float*)d_in[12];
    const float* b_dec   = (const float*)d_in[13];
    float* out = (float*)d_out;

    float* t_  = (float*)d_ws;                    // [6400,768] fp32
    bf16* g_   = (bf16*)(t_ + 6400L*768);         // [6400,768]
    bf16* qkh  = g_ + 6400L*768;                  // [6400,4608] = q|k|h (aq|ak overwrite q|k)
    bf16* qT   = qkh + 6400L*4608;                // [384,64,256]
    bf16* kT   = qT + 384L*16384;                 // [384,64,256]
    float* p0  = (float*)(kT + 384L*16384);       // [6400,768] split-K partial z=0
    float* p1  = p0 + 6400L*768;                  // [6400,768] split-K partial z=1
    bf16* B1   = (bf16*)(p1 + 6400L*768);         // [4608,768]  wq|wk|whop
    bf16* B2   = B1 + 4608L*768;                  // [768,4608]  = B1^T
    bf16* we_  = B2 + 768L*4608;                  // [768,768]
    bf16* wd_  = we_ + 768L*768;                  // [768,768]
    // z=2 partial aliases qT/kT scratch: that region (25.2 MB >= 19.7 MB) is
    // dead between attn_k (last reader) and the next step's pack_k (next
    // writer, which rewrites ALL cells incl. zero pads); wide_gemm<1> fills
    // it fully before ln_k reads it.
    float* p2  = (float*)qT;

    dim3 blk(256);
    dim3 lblk(192);
    const long ZOFF = 6400L*768;

    // fused prologue: 5 weight converts + x pad + cls row in ONE launch
    pre_k<<<dim3(37728), blk, 0, stream>>>(wq, wk, w_hop, w_enc, w_dec, x, cls_tok, pos,
                                           B1, we_, wd_, g_, t_);
    tr_k<<<dim3(144,24), blk, 0, stream>>>((const short*)B1, (short*)B2);

    big_gemm<2><<<dim3(300), blk, 0, stream>>>((const short*)g_, 768, (const short*)we_, 768,
                                               t_, nullptr, 768, 768, 6, 50, 0, 0, b_enc, pos);

    for (int step=0; step<12; step++){
        ln_k<<<dim3(6304), lblk, 0, stream>>>(t_, g_, p0, p1, p2, eln_g, eln_b, 1, 0, step>0, 1);
        // [6400,4608] = g @ [wq|wk|whop]^T, K=768: 25 x 36 = 900 blocks
        wide_gemm<0><<<dim3(900), blk, 0, stream>>>((const short*)g_, 768, (const short*)B1, 768,
                                                    nullptr, nullptr, qkh, 4608, 768, 36, 25, 1536, 0);
        pack_k<<<dim3(384,4), blk, 0, stream>>>((const short*)qkh, (short*)qT, (short*)kT);
        attn_k<<<dim3(384), blk, 0, stream>>>((short*)qkh, (const short*)qT, (const short*)kT);
        // [6400,768] = [aq|ak|relu h] @ B2^T-form, K=4608 split 3: 150 x 3 blocks
        wide_gemm<1><<<dim3(150,1,3), blk, 0, stream>>>((const short*)qkh, 4608, (const short*)B2, 4608,
                                                        p0, p2, nullptr, 768, 4608, 6, 25, 0, ZOFF);
    }

    ln_k<<<dim3(6272), lblk, 0, stream>>>(t_, g_, p0, p1, p2, dln_w, dln_b, 0, 1, 1, 0);
    big_gemm<3><<<dim3(300), blk, 0, stream>>>((const short*)g_, 768, (const short*)wd_, 768,
                                               out, nullptr, 768, 768, 6, 50, 0, 0, b_dec, nullptr);
}